// Round 6
// baseline (300.490 us; speedup 1.0000x reference)
//
#include <hip/hip_runtime.h>

#define N_NODES 100000
#define F_IN 256
#define F_OUT 128
#define NB2 391      // ceil(N_NODES/256) coarse buckets of 256 rows
#define CAPB 4608    // per-bucket cap: mean 4096, sigma 64 -> +8 sigma

typedef __attribute__((ext_vector_type(8))) short bf16x8;
typedef __attribute__((ext_vector_type(4))) float f32x4;
typedef __attribute__((ext_vector_type(2))) float f32x2;

__device__ inline unsigned short f2bf(float f) {  // RNE fp32->bf16
  unsigned u = __builtin_bit_cast(unsigned, f);
  u += 0x7fffu + ((u >> 16) & 1u);
  return (unsigned short)(u >> 16);
}

// ---------------- GEMM (bf16 MFMA): transformed[n][o] = x[n][:]·W[o][:] + b[o]
// 64x128 M-tile. ALL FOUR K-steps' x/W data prefetched into registers in the
// prologue (one latency event per block instead of one per K-step); the
// K-loop is pure regs->LDS->MFMA.
__global__ __launch_bounds__(256, 2) void gemm_kernel(
    const float* __restrict__ x, const unsigned short* __restrict__ wbf,
    const float* __restrict__ bias, unsigned short* __restrict__ tout) {
  __shared__ unsigned short As[64][72];
  __shared__ unsigned short Bs[128][72];
  const int tid = threadIdx.x;
  const int wave = tid >> 6, lane = tid & 63;
  const int quad = lane >> 4, l16 = lane & 15;
  const int mw = (wave >> 1) * 32, nw = (wave & 1) * 64;
  const int blockM = blockIdx.x * 64;

  f32x4 acc[2][4];
#pragma unroll
  for (int i = 0; i < 2; ++i)
#pragma unroll
    for (int j = 0; j < 4; ++j) acc[i][j] = (f32x4){0.f, 0.f, 0.f, 0.f};

  const int row_s = tid >> 4;  // 0..15 : A staging
  const int c4 = tid & 15;     // 0..15 (x4 floats = 64 cols)
  const int row_b = tid >> 3;  // 0..31 : B staging
  const int c8 = tid & 7;      // 0..7  (x8 shorts = 64 cols)

  // -------- prologue: issue the block's ENTIRE global traffic ----------
  float4 pa[4][4];   // [kstep][i]
  bf16x8 pb[4][4];
#pragma unroll
  for (int k = 0; k < 4; ++k) {
#pragma unroll
    for (int i = 0; i < 4; ++i) {
      int node = blockM + row_s + i * 16;
      pa[k][i] = make_float4(0.f, 0.f, 0.f, 0.f);
      if (node < N_NODES)
        pa[k][i] = *(const float4*)(x + (size_t)node * F_IN + k * 64 + c4 * 4);
      pb[k][i] = *(const bf16x8*)(wbf + (row_b + i * 32) * F_IN + k * 64 + c8 * 8);
    }
  }

#pragma unroll
  for (int k = 0; k < 4; ++k) {
#pragma unroll
    for (int i = 0; i < 4; ++i) {
      unsigned short* p = &As[row_s + i * 16][c4 * 4];
      p[0] = f2bf(pa[k][i].x); p[1] = f2bf(pa[k][i].y);
      p[2] = f2bf(pa[k][i].z); p[3] = f2bf(pa[k][i].w);
    }
#pragma unroll
    for (int i = 0; i < 4; ++i)
      *(bf16x8*)&Bs[row_b + i * 32][c8 * 8] = pb[k][i];
    __syncthreads();
#pragma unroll
    for (int ks = 0; ks < 2; ++ks) {
      bf16x8 a[2], bb[4];
#pragma unroll
      for (int t = 0; t < 2; ++t)
        a[t] = *(const bf16x8*)&As[mw + t * 16 + l16][ks * 32 + quad * 8];
#pragma unroll
      for (int t = 0; t < 4; ++t)
        bb[t] = *(const bf16x8*)&Bs[nw + t * 16 + l16][ks * 32 + quad * 8];
#pragma unroll
      for (int i = 0; i < 2; ++i)
#pragma unroll
        for (int j = 0; j < 4; ++j)
          acc[i][j] = __builtin_amdgcn_mfma_f32_16x16x32_bf16(a[i], bb[j], acc[i][j], 0, 0, 0);
    }
    __syncthreads();
  }
#pragma unroll
  for (int i = 0; i < 2; ++i) {
#pragma unroll
    for (int j = 0; j < 4; ++j) {
      int o = nw + j * 16 + l16;
      float bv = bias[o];
#pragma unroll
      for (int r = 0; r < 4; ++r) {
        int node = blockM + mw + i * 16 + quad * 4 + r;
        if (node < N_NODES)
          tout[(size_t)node * F_OUT + o] = f2bf(acc[i][j][r] + bv);
      }
    }
  }
}

// ---------------- Phase A: LDS-aggregated bucket append + W fp32->bf16 -----
__global__ __launch_bounds__(512) void phaseA_kernel(
    const int* __restrict__ rows, const int* __restrict__ cols,
    const float* __restrict__ vals, int* __restrict__ cursor,
    int2* __restrict__ staging, int E, int edgeBlocks,
    const float* __restrict__ W, unsigned short* __restrict__ wbf) {
  if (blockIdx.x >= edgeBlocks) {  // 16 tail blocks: W convert (8192 float4)
    int t = (blockIdx.x - edgeBlocks) * 512 + threadIdx.x;
    float4 v = *(const float4*)(W + (size_t)t * 4);
    unsigned short* p = wbf + (size_t)t * 4;
    p[0] = f2bf(v.x); p[1] = f2bf(v.y); p[2] = f2bf(v.z); p[3] = f2bf(v.w);
    return;
  }
  __shared__ int hist[NB2];
  const int t = threadIdx.x;
  for (int i = t; i < NB2; i += 512) hist[i] = 0;
  __syncthreads();
  const int b0 = blockIdx.x * 4096;
  int rr[8];
#pragma unroll
  for (int k = 0; k < 8; ++k) {
    int idx = b0 + k * 512 + t;
    rr[k] = -1;
    if (idx < E) {
      rr[k] = rows[idx];
      atomicAdd(&hist[rr[k] >> 8], 1);
    }
  }
  __syncthreads();
  // one global atomic per non-empty bucket; hist becomes absolute LDS cursor
  for (int i = t; i < NB2; i += 512) {
    int c = hist[i];
    hist[i] = c ? atomicAdd(&cursor[i * 16], c) : 0;
  }
  __syncthreads();
#pragma unroll
  for (int k = 0; k < 8; ++k) {
    int idx = b0 + k * 512 + t;
    if (idx < E) {
      int c = cols[idx];
      float v = vals[idx];
      int bkt = rr[k] >> 8;
      int slot = atomicAdd(&hist[bkt], 1);
      if (slot < CAPB)
        staging[(size_t)bkt * CAPB + slot] =
            make_int2(((rr[k] & 255) << 17) | c, __float_as_int(v));
    }
  }
}

// ---------------- Phase B: bucket -> final CSR (per-row runs) --------------
__global__ __launch_bounds__(512) void phaseB_kernel(
    const int2* __restrict__ staging, const int* __restrict__ cursor,
    int* __restrict__ allocCtr, int2* __restrict__ edata,
    int* __restrict__ rowOff, int* __restrict__ rowCnt) {
  const int b = blockIdx.x;
  const int t = threadIdx.x;
  __shared__ int rc[256];
  __shared__ int ws[4];
  __shared__ int base_s;
  if (t < 256) rc[t] = 0;
  __syncthreads();
  const int cnt = min(cursor[b * 16], CAPB);
  const int2* sp = staging + (size_t)b * CAPB;
  for (int i = t; i < cnt; i += 512)
    atomicAdd(&rc[sp[i].x >> 17], 1);
  __syncthreads();
  int v = 0, sum = 0;
  if (t < 256) {
    v = rc[t];
    sum = v;  // inclusive scan within each 64-lane segment
#pragma unroll
    for (int off = 1; off < 64; off <<= 1) {
      int u = __shfl_up(sum, off, 64);
      if ((t & 63) >= off) sum += u;
    }
    if ((t & 63) == 63) ws[t >> 6] = sum;
  }
  __syncthreads();
  if (t == 0) base_s = atomicAdd(allocCtr, ws[0] + ws[1] + ws[2] + ws[3]);
  __syncthreads();
  if (t < 256) {
    int carry = base_s;
#pragma unroll
    for (int j = 0; j < 4; ++j)
      if (j < (t >> 6)) carry += ws[j];
    int off0 = carry + sum - v;  // absolute exclusive offset in edata
    rc[t] = off0;                // becomes pass-2 cursor
    int row = b * 256 + t;
    if (row < N_NODES) {
      rowOff[row] = off0;
      rowCnt[row] = v;
    }
  }
  __syncthreads();
  for (int i = t; i < cnt; i += 512) {
    int2 e = sp[i];
    int rl = e.x >> 17;
    int dst = atomicAdd(&rc[rl], 1);
    edata[dst] = make_int2(e.x & 0x1FFFF, e.y);
  }
}

// ---------------- SpMM: one wave per row, scalarized broadcast gathers -----
// Per edge, every lane uses the SAME (col,val): readlane -> SGPR, so the
// gather is global_load_dword with SGPR base + fixed lane offset (no per-lane
// 64-bit VALU address math, no ds_bpermute). 16 loads in flight per wave.
// out is write-once -> non-temporal store (keeps tb lines resident in L2).
__global__ __launch_bounds__(256) void spmm_kernel(
    const unsigned short* __restrict__ tb, const int2* __restrict__ edata,
    const int* __restrict__ rowOff, const int* __restrict__ rowCnt,
    float* __restrict__ out) {
  int wave = (blockIdx.x * 256 + threadIdx.x) >> 6;
  int lane = threadIdx.x & 63;
  if (wave >= N_NODES) return;
  int start = rowOff[wave];
  int n = rowCnt[wave];
  float2 acc = make_float2(0.f, 0.f);
  for (int base = 0; base < n; base += 64) {
    int m = n - base;
    if (m > 64) m = 64;
    int c = 0;
    float v = 0.f;
    if (lane < m) {
      long long raw = __builtin_nontemporal_load((const long long*)(edata + start + base + lane));
      int2 e = __builtin_bit_cast(int2, raw);
      c = e.x;
      v = __builtin_bit_cast(float, e.y);
    }
    // groups of 16: 16 independent scalar-addressed loads in flight. Tail
    // lanes (j>=m) hold c=0,v=0 -> safe load of hot row 0, FMA contributes 0.
    for (int j0 = 0; j0 < m; j0 += 16) {
      unsigned t[16];
      float vj[16];
#pragma unroll
      for (int jj = 0; jj < 16; ++jj) {
        int cj = __builtin_amdgcn_readlane(c, j0 + jj);               // SGPR
        vj[jj] = __builtin_bit_cast(
            float, __builtin_amdgcn_readlane(__builtin_bit_cast(int, v), j0 + jj));
        t[jj] = *(const unsigned*)(tb + (size_t)cj * F_OUT + lane * 2);
      }
#pragma unroll
      for (int jj = 0; jj < 16; ++jj) {
        acc.x = fmaf(vj[jj], __builtin_bit_cast(float, t[jj] << 16), acc.x);
        acc.y = fmaf(vj[jj], __builtin_bit_cast(float, t[jj] & 0xffff0000u), acc.y);
      }
    }
  }
  f32x2 accv = {acc.x, acc.y};
  __builtin_nontemporal_store(accv, (f32x2*)out + (size_t)wave * 64 + lane);
}

extern "C" void kernel_launch(void* const* d_in, const int* in_sizes, int n_in,
                              void* d_out, int out_size, void* d_ws, size_t ws_size,
                              hipStream_t stream) {
  const float* x    = (const float*)d_in[0];
  const int*   rows = (const int*)d_in[1];
  const int*   cols = (const int*)d_in[2];
  const float* vals = (const float*)d_in[3];
  const float* W    = (const float*)d_in[4];
  const float* b    = (const float*)d_in[5];
  float* out = (float*)d_out;
  const int E = in_sizes[1];

  // ws layout: region0 = tb (25.6MB) ALIASED with staging (NB2*CAPB*8 =
  // 14.4MB; gemm runs after phaseB) | edata | cursor+allocCtr | rowOff |
  // rowCnt | wbf (bf16 W, 64KB)
  const size_t region0 = ((size_t)N_NODES * F_OUT * 2 + 255) & ~(size_t)255;
  unsigned short* tb = (unsigned short*)d_ws;
  int2* staging  = (int2*)d_ws;
  int2* edata    = (int2*)((char*)d_ws + region0);
  int* cursor    = (int*)(edata + E);
  int* allocCtr  = cursor + NB2 * 16;
  int* rowOff    = allocCtr + 16;
  int* rowCnt    = rowOff + N_NODES;
  unsigned short* wbf = (unsigned short*)(rowCnt + N_NODES);

  hipMemsetAsync(cursor, 0, ((size_t)NB2 * 16 + 16) * sizeof(int), stream);

  const int edgeBlocks = (E + 4095) / 4096;
  phaseA_kernel<<<edgeBlocks + 16, 512, 0, stream>>>(rows, cols, vals, cursor, staging,
                                                     E, edgeBlocks, W, wbf);
  phaseB_kernel<<<NB2, 512, 0, stream>>>(staging, cursor, allocCtr, edata, rowOff, rowCnt);
  gemm_kernel<<<(N_NODES + 63) / 64, 256, 0, stream>>>(x, wbf, b, tb);  // overwrites staging
  spmm_kernel<<<(N_NODES + 3) / 4, 256, 0, stream>>>(tb, edata, rowOff, rowCnt, out);
}